// Round 1
// baseline (1312.670 us; speedup 1.0000x reference)
//
#include <hip/hip_runtime.h>
#include <hip/hip_bf16.h>

#define IN_F 128
#define OUT_F 32

// ---------------- Kernel 1: h = x @ W  (W staged in LDS) ----------------
// block = 256 threads: 32 rows x 8 col-groups (float4 each).
__global__ void gcn_gemm_h(const float* __restrict__ x, const float* __restrict__ W,
                           float* __restrict__ h, int n_rows)
{
    __shared__ float Wl[IN_F * OUT_F];              // 16 KB
    const int tid = threadIdx.x;

    // cooperative load of W (4096 floats = 1024 float4)
    const float4* W4 = (const float4*)W;
    float4* Wl4 = (float4*)Wl;
    #pragma unroll
    for (int i = 0; i < 4; ++i)
        Wl4[tid + i * 256] = W4[tid + i * 256];
    __syncthreads();

    const int c4   = tid & 7;        // which float4 of the 32 output cols
    const int rloc = tid >> 3;       // 0..31
    const int row  = blockIdx.x * 32 + rloc;
    if (row >= n_rows) return;

    const float4* xr = (const float4*)(x + (size_t)row * IN_F);
    float4 acc = {0.f, 0.f, 0.f, 0.f};

    #pragma unroll
    for (int k4 = 0; k4 < IN_F / 4; ++k4) {
        const float4 xv = xr[k4];
        #pragma unroll
        for (int j = 0; j < 4; ++j) {
            const int k = k4 * 4 + j;
            const float4 wv = *(const float4*)(&Wl[k * OUT_F + c4 * 4]);
            const float xs = (&xv.x)[j];
            acc.x += xs * wv.x;
            acc.y += xs * wv.y;
            acc.z += xs * wv.z;
            acc.w += xs * wv.w;
        }
    }
    *(float4*)(&h[(size_t)row * OUT_F + c4 * 4]) = acc;
}

// ---------------- Kernel 2: scatter-add over edges ----------------
// one thread per (edge, 4-channel group): 8 threads/edge.
__global__ void gcn_scatter(const float* __restrict__ h,
                            const int* __restrict__ esrc,
                            const int* __restrict__ edst,
                            const float* __restrict__ ew,
                            float* __restrict__ out,
                            long long total_units)
{
    long long u = (long long)blockIdx.x * blockDim.x + threadIdx.x;
    if (u >= total_units) return;
    const int e = (int)(u >> 3);
    const int g = (int)(u & 7);

    const int s  = esrc[e];
    const int d  = edst[e];
    const float w = ew[e];

    const float4 hv = *(const float4*)(&h[(size_t)s * OUT_F + g * 4]);
    float* op = out + (size_t)d * OUT_F + g * 4;
    atomicAdd(op + 0, w * hv.x);
    atomicAdd(op + 1, w * hv.y);
    atomicAdd(op + 2, w * hv.z);
    atomicAdd(op + 3, w * hv.w);
}

// ---------------- Fallback (ws too small): fuse GEMM into scatter ----------------
// one thread per (edge, channel): dot(x[src], W[:,c]) on the fly. Slow but correct.
__global__ void gcn_fused_fallback(const float* __restrict__ x, const float* __restrict__ W,
                                   const int* __restrict__ esrc,
                                   const int* __restrict__ edst,
                                   const float* __restrict__ ew,
                                   float* __restrict__ out,
                                   long long total_units)
{
    __shared__ float Wl[IN_F * OUT_F];
    const int tid = threadIdx.x;
    const float4* W4 = (const float4*)W;
    float4* Wl4 = (float4*)Wl;
    #pragma unroll
    for (int i = 0; i < 4; ++i)
        Wl4[tid + i * 256] = W4[tid + i * 256];
    __syncthreads();

    long long u = (long long)blockIdx.x * blockDim.x + threadIdx.x;
    if (u >= total_units) return;
    const int e = (int)(u >> 5);
    const int c = (int)(u & 31);

    const int s  = esrc[e];
    const int d  = edst[e];
    const float w = ew[e];

    const float4* xr = (const float4*)(x + (size_t)s * IN_F);
    float acc = 0.f;
    #pragma unroll
    for (int k4 = 0; k4 < IN_F / 4; ++k4) {
        const float4 xv = xr[k4];
        acc += xv.x * Wl[(k4 * 4 + 0) * OUT_F + c];
        acc += xv.y * Wl[(k4 * 4 + 1) * OUT_F + c];
        acc += xv.z * Wl[(k4 * 4 + 2) * OUT_F + c];
        acc += xv.w * Wl[(k4 * 4 + 3) * OUT_F + c];
    }
    atomicAdd(out + (size_t)d * OUT_F + c, w * acc);
}

extern "C" void kernel_launch(void* const* d_in, const int* in_sizes, int n_in,
                              void* d_out, int out_size, void* d_ws, size_t ws_size,
                              hipStream_t stream)
{
    const float* x  = (const float*)d_in[0];
    const float* W  = (const float*)d_in[1];
    const int* esrc = (const int*)d_in[2];
    const int* edst = (const int*)d_in[3];
    const float* ew = (const float*)d_in[4];
    float* out = (float*)d_out;

    const int n_nodes = in_sizes[0] / IN_F;
    const int n_edges = in_sizes[2];

    // zero the (0xAA-poisoned) output — we accumulate into it
    hipMemsetAsync(d_out, 0, (size_t)out_size * sizeof(float), stream);

    const size_t h_bytes = (size_t)n_nodes * OUT_F * sizeof(float);
    if (ws_size >= h_bytes) {
        float* h = (float*)d_ws;
        const int gemm_blocks = (n_nodes + 31) / 32;
        gcn_gemm_h<<<gemm_blocks, 256, 0, stream>>>(x, W, h, n_nodes);

        const long long total_units = (long long)n_edges * 8;
        const int sblocks = (int)((total_units + 255) / 256);
        gcn_scatter<<<sblocks, 256, 0, stream>>>(h, esrc, edst, ew, out, total_units);
    } else {
        const long long total_units = (long long)n_edges * 32;
        const int fblocks = (int)((total_units + 255) / 256);
        gcn_fused_fallback<<<fblocks, 256, 0, stream>>>(x, W, esrc, edst, ew, out, total_units);
    }
}

// Round 2
// 559.902 us; speedup vs baseline: 2.3445x; 2.3445x over previous
//
#include <hip/hip_runtime.h>
#include <hip/hip_bf16.h>

#define IN_F 128
#define OUT_F 32

// ---------------- Kernel 1: h = x @ W  (W staged in LDS) ----------------
__global__ void gcn_gemm_h(const float* __restrict__ x, const float* __restrict__ W,
                           float* __restrict__ h, int n_rows)
{
    __shared__ float Wl[IN_F * OUT_F];              // 16 KB
    const int tid = threadIdx.x;
    const float4* W4 = (const float4*)W;
    float4* Wl4 = (float4*)Wl;
    #pragma unroll
    for (int i = 0; i < 4; ++i)
        Wl4[tid + i * 256] = W4[tid + i * 256];
    __syncthreads();

    const int c4   = tid & 7;
    const int rloc = tid >> 3;
    const int row  = blockIdx.x * 32 + rloc;
    if (row >= n_rows) return;

    const float4* xr = (const float4*)(x + (size_t)row * IN_F);
    float4 acc = {0.f, 0.f, 0.f, 0.f};
    #pragma unroll
    for (int k4 = 0; k4 < IN_F / 4; ++k4) {
        const float4 xv = xr[k4];
        #pragma unroll
        for (int j = 0; j < 4; ++j) {
            const int k = k4 * 4 + j;
            const float4 wv = *(const float4*)(&Wl[k * OUT_F + c4 * 4]);
            const float xs = (&xv.x)[j];
            acc.x += xs * wv.x;
            acc.y += xs * wv.y;
            acc.z += xs * wv.z;
            acc.w += xs * wv.w;
        }
    }
    *(float4*)(&h[(size_t)row * OUT_F + c4 * 4]) = acc;
}

// ---------------- CSR build: count ----------------
__global__ void gcn_count(const int* __restrict__ edst, int* __restrict__ cnt, int n_edges)
{
    int e = blockIdx.x * blockDim.x + threadIdx.x;
    if (e < n_edges) atomicAdd(&cnt[edst[e]], 1);
}

// ---------------- Scan step 1: per-1024-chunk exclusive scan + chunk sums ----------------
__global__ void gcn_scan1(const int* __restrict__ cnt, int* __restrict__ offs,
                          int* __restrict__ partial, int n)
{
    __shared__ int sh[256];
    const int tid  = threadIdx.x;
    const int base = blockIdx.x * 1024;
    const int idx  = base + tid * 4;

    int4 v = {0, 0, 0, 0};
    if (idx + 3 < n) v = *(const int4*)(cnt + idx);
    else {
        if (idx     < n) v.x = cnt[idx];
        if (idx + 1 < n) v.y = cnt[idx + 1];
        if (idx + 2 < n) v.z = cnt[idx + 2];
        if (idx + 3 < n) v.w = cnt[idx + 3];
    }
    const int s = v.x + v.y + v.z + v.w;
    sh[tid] = s;
    __syncthreads();
    for (int off = 1; off < 256; off <<= 1) {
        int t = (tid >= off) ? sh[tid - off] : 0;
        __syncthreads();
        sh[tid] += t;
        __syncthreads();
    }
    const int excl = sh[tid] - s;
    if (tid == 255) partial[blockIdx.x] = sh[255];

    const int e0 = excl, e1 = e0 + v.x, e2 = e1 + v.y, e3 = e2 + v.z;
    if (idx     < n) offs[idx]     = e0;
    if (idx + 1 < n) offs[idx + 1] = e1;
    if (idx + 2 < n) offs[idx + 2] = e2;
    if (idx + 3 < n) offs[idx + 3] = e3;
}

// ---------------- Scan step 2: scan the chunk sums (single block, up to 256 chunks) ----------------
__global__ void gcn_scan2(int* __restrict__ partial, int nb)
{
    __shared__ int sh[256];
    const int tid = threadIdx.x;
    const int v = (tid < nb) ? partial[tid] : 0;
    sh[tid] = v;
    __syncthreads();
    for (int off = 1; off < 256; off <<= 1) {
        int t = (tid >= off) ? sh[tid - off] : 0;
        __syncthreads();
        sh[tid] += t;
        __syncthreads();
    }
    if (tid < nb) partial[tid] = sh[tid] - v;   // exclusive
}

// ---------------- Scan step 3: add chunk offsets, copy to cursor, write offs[n] ----------------
__global__ void gcn_scan3(int* __restrict__ offs, const int* __restrict__ partial,
                          int* __restrict__ cursor, int n, int total)
{
    const int idx = blockIdx.x * 1024 + threadIdx.x * 4;
    const int add = partial[blockIdx.x];
    #pragma unroll
    for (int j = 0; j < 4; ++j) {
        if (idx + j < n) {
            const int o = offs[idx + j] + add;
            offs[idx + j]   = o;
            cursor[idx + j] = o;
        }
    }
    if (blockIdx.x == 0 && threadIdx.x == 0) offs[n] = total;
}

// ---------------- Fill: scatter (src, w) pairs into CSR slots ----------------
__global__ void gcn_fill(const int* __restrict__ esrc, const int* __restrict__ edst,
                         const float* __restrict__ ew, int* __restrict__ cursor,
                         int2* __restrict__ pairs, int n_edges)
{
    int e = blockIdx.x * blockDim.x + threadIdx.x;
    if (e < n_edges) {
        const int d   = edst[e];
        const int pos = atomicAdd(&cursor[d], 1);
        pairs[pos] = make_int2(esrc[e], __float_as_int(ew[e]));
    }
}

// ---------------- Gather: per-dst register accumulation, no atomics ----------------
// 32 threads per node (one per channel), 8 nodes per 256-thread block.
__global__ void gcn_gather(const float* __restrict__ h, const int* __restrict__ offs,
                           const int2* __restrict__ pairs, float* __restrict__ out, int n)
{
    const int node = blockIdx.x * 8 + (threadIdx.x >> 5);
    const int c    = threadIdx.x & 31;
    if (node >= n) return;
    const int s = offs[node];
    const int t = offs[node + 1];
    float acc = 0.f;
    for (int i = s; i < t; ++i) {
        const int2 p = pairs[i];
        acc += __int_as_float(p.y) * h[(size_t)p.x * OUT_F + c];
    }
    out[(size_t)node * OUT_F + c] = acc;
}

// ---------------- Fallback: previous atomic scatter ----------------
__global__ void gcn_scatter(const float* __restrict__ h,
                            const int* __restrict__ esrc,
                            const int* __restrict__ edst,
                            const float* __restrict__ ew,
                            float* __restrict__ out,
                            long long total_units)
{
    long long u = (long long)blockIdx.x * blockDim.x + threadIdx.x;
    if (u >= total_units) return;
    const int e = (int)(u >> 3);
    const int g = (int)(u & 7);
    const int s  = esrc[e];
    const int d  = edst[e];
    const float w = ew[e];
    const float4 hv = *(const float4*)(&h[(size_t)s * OUT_F + g * 4]);
    float* op = out + (size_t)d * OUT_F + g * 4;
    atomicAdd(op + 0, w * hv.x);
    atomicAdd(op + 1, w * hv.y);
    atomicAdd(op + 2, w * hv.z);
    atomicAdd(op + 3, w * hv.w);
}

static inline size_t align_up(size_t v, size_t a) { return (v + a - 1) & ~(a - 1); }

extern "C" void kernel_launch(void* const* d_in, const int* in_sizes, int n_in,
                              void* d_out, int out_size, void* d_ws, size_t ws_size,
                              hipStream_t stream)
{
    const float* x  = (const float*)d_in[0];
    const float* W  = (const float*)d_in[1];
    const int* esrc = (const int*)d_in[2];
    const int* edst = (const int*)d_in[3];
    const float* ew = (const float*)d_in[4];
    float* out = (float*)d_out;

    const int n_nodes = in_sizes[0] / IN_F;
    const int n_edges = in_sizes[2];

    // ws layout
    const size_t h_bytes      = align_up((size_t)n_nodes * OUT_F * sizeof(float), 256);
    const size_t offs_bytes   = align_up(((size_t)n_nodes + 1) * sizeof(int), 256);
    const size_t cursor_bytes = align_up((size_t)n_nodes * sizeof(int), 256);
    const size_t part_bytes   = align_up(256 * sizeof(int), 256);
    const size_t pairs_bytes  = align_up((size_t)n_edges * sizeof(int2), 256);
    const size_t need = h_bytes + offs_bytes + cursor_bytes + part_bytes + pairs_bytes;

    const int n_chunks = (n_nodes + 1023) / 1024;

    if (ws_size >= need && n_chunks <= 256) {
        char* p = (char*)d_ws;
        float* h    = (float*)p;              p += h_bytes;
        int* offs   = (int*)p;                p += offs_bytes;
        int* cursor = (int*)p;                p += cursor_bytes;
        int* part   = (int*)p;                p += part_bytes;
        int2* pairs = (int2*)p;

        // counts must be zero each call (ws is not re-poisoned between replays)
        hipMemsetAsync(cursor, 0, (size_t)n_nodes * sizeof(int), stream);  // use cursor as counts first

        const int gemm_blocks = (n_nodes + 31) / 32;
        gcn_gemm_h<<<gemm_blocks, 256, 0, stream>>>(x, W, h, n_nodes);

        const int eblocks = (n_edges + 255) / 256;
        gcn_count<<<eblocks, 256, 0, stream>>>(edst, cursor, n_edges);

        gcn_scan1<<<n_chunks, 256, 0, stream>>>(cursor, offs, part, n_nodes);
        gcn_scan2<<<1, 256, 0, stream>>>(part, n_chunks);
        gcn_scan3<<<n_chunks, 256, 0, stream>>>(offs, part, cursor, n_nodes, n_edges);

        gcn_fill<<<eblocks, 256, 0, stream>>>(esrc, edst, ew, cursor, pairs, n_edges);

        const int gblocks = (n_nodes + 7) / 8;
        gcn_gather<<<gblocks, 256, 0, stream>>>(h, offs, pairs, out, n_nodes);
    } else if (ws_size >= (size_t)n_nodes * OUT_F * sizeof(float)) {
        hipMemsetAsync(d_out, 0, (size_t)out_size * sizeof(float), stream);
        float* h = (float*)d_ws;
        const int gemm_blocks = (n_nodes + 31) / 32;
        gcn_gemm_h<<<gemm_blocks, 256, 0, stream>>>(x, W, h, n_nodes);
        const long long total_units = (long long)n_edges * 8;
        const int sblocks = (int)((total_units + 255) / 256);
        gcn_scatter<<<sblocks, 256, 0, stream>>>(h, esrc, edst, ew, out, total_units);
    }
}